// Round 14
// baseline (442.154 us; speedup 1.0000x reference)
//
#include <hip/hip_runtime.h>

// R14 = R10 (best, 318us) + two micro-fixes:
//  - LDS pitches re-padded: HP 72->76 halfs (152B rows), XP 40->44 (88B rows)
//    -> ds_read_b128 / f16x4 writes <=2-way bank aliasing (targets the
//    persistent 1.9e7 SQ_LDS_BANK_CONFLICT).
//  - bias rides as MFMA C operand (kills per-step v_mov acc-init; FP-identical).
// Structure unchanged: 8-wave layer-split block, BB=16, skewed layers,
// 1 barrier/step, weights in regs, rational 7-trans packed-f32 activations.

#define TT 256
#define II 14
#define BB 16
#define NTHREADS 512
#define XP 44        // xs row pitch (halfs), 88B
#define HP 76        // h row pitch (halfs), 152B
#define HSTR 1216    // halfs per H buffer (16*76)
#define XSTR 704     // halfs per XS buffer (16*44)
#define LOG2E 1.44269504088896340736f

typedef _Float16 f16x8 __attribute__((ext_vector_type(8)));
typedef _Float16 f16x4 __attribute__((ext_vector_type(4)));
typedef _Float16 f16x2 __attribute__((ext_vector_type(2)));
typedef float f32x4 __attribute__((ext_vector_type(4)));
typedef float f32x2 __attribute__((ext_vector_type(2)));

__device__ __forceinline__ f32x4 MFMA16(f16x8 a, f16x8 b, f32x4 c) {
  return __builtin_amdgcn_mfma_f32_16x16x32_f16(a, b, c, 0, 0, 0);
}

__device__ __forceinline__ float ex2(float x) {
#if __has_builtin(__builtin_amdgcn_exp2f)
  return __builtin_amdgcn_exp2f(x);
#else
  float r; asm("v_exp_f32 %0, %1" : "=v"(r) : "v"(x)); return r;
#endif
}
__device__ __forceinline__ float rcp_(float x) {
#if __has_builtin(__builtin_amdgcn_rcpf)
  return __builtin_amdgcn_rcpf(x);
#else
  float r; asm("v_rcp_f32 %0, %1" : "=v"(r) : "v"(x)); return r;
#endif
}
__device__ __forceinline__ f16x2 cvt_pk(float a, float b) {
#if __has_builtin(__builtin_amdgcn_cvt_pkrtz)
  return __builtin_bit_cast(f16x2, __builtin_amdgcn_cvt_pkrtz(a, b));
#else
  f16x2 r; r[0] = (_Float16)a; r[1] = (_Float16)b; return r;
#endif
}

// Pre-scaled gates (i,f,o: *-log2e ; g: *2log2e), u = 2^s (R7 derivation).
__device__ __forceinline__ f16x4 lstm_act(f32x4 si, f32x4 sf, f32x4 sg, f32x4 so,
                                          f32x4& cs) {
  f16x4 hp;
#pragma unroll
  for (int p = 0; p < 2; ++p) {
    f32x2 ui, uf, ug, uo;
    ui.x = ex2(si[2 * p]); ui.y = ex2(si[2 * p + 1]);
    uf.x = ex2(sf[2 * p]); uf.y = ex2(sf[2 * p + 1]);
    ug.x = ex2(sg[2 * p]); ug.y = ex2(sg[2 * p + 1]);
    uo.x = ex2(so[2 * p]); uo.y = ex2(so[2 * p + 1]);
    const f32x2 one = {1.0f, 1.0f};
    const f32x2 fi = ui + one;
    const f32x2 ff = uf + one;
    const f32x2 fg = ug + one;
    const f32x2 pig = fi * fg;
    f32x2 cv; cv.x = cs[2 * p]; cv.y = cs[2 * p + 1];
    const f32x2 num = cv * pig + (ug - one) * ff;
    const f32x2 den = pig * ff;
    f32x2 rd; rd.x = rcp_(den.x); rd.y = rcp_(den.y);
    const f32x2 c = num * rd;
    cs[2 * p] = c.x; cs[2 * p + 1] = c.y;
    const f32x2 ctl = c * (f32x2){2.0f * LOG2E, 2.0f * LOG2E};
    f32x2 ut; ut.x = ex2(ctl.x); ut.y = ex2(ctl.y);
    const f32x2 dh = (uo + one) * (ut + one);
    f32x2 rh; rh.x = rcp_(dh.x); rh.y = rcp_(dh.y);
    const f32x2 h = (ut - one) * rh;
    const f16x2 h2 = cvt_pk(h.x, h.y);
    hp[2 * p] = h2[0];
    hp[2 * p + 1] = h2[1];
  }
  return hp;
}

__global__ void __launch_bounds__(NTHREADS, 4) fused_lstm(
    const float* __restrict__ x,
    const float* __restrict__ w_ih0, const float* __restrict__ w_hh0,
    const float* __restrict__ b_ih0, const float* __restrict__ b_hh0,
    const float* __restrict__ w_ih1, const float* __restrict__ w_hh1,
    const float* __restrict__ b_ih1, const float* __restrict__ b_hh1,
    const float* __restrict__ w_fc1, const float* __restrict__ b_fc1,
    const float* __restrict__ w_fc2, const float* __restrict__ b_fc2,
    float* __restrict__ out) {
  // LDS bytes: H1[2] @0 (2x2432) ; H0[2] @4864 (2x2432) ; XS[2] @9728 (2x1408)
  __shared__ char smem[12544];
  _Float16* H1 = (_Float16*)smem;
  _Float16* H0 = (_Float16*)(smem + 4864);
  _Float16* XS = (_Float16*)(smem + 9728);

  const int tid = threadIdx.x;
  const int wv = tid >> 6;
  const int grp = wv >> 2;   // 0: layer-0 waves, 1: layer-1 waves
  const int wl = wv & 3;     // hidden-tile index (16 units)
  const int l = tid & 63;
  const int row16 = l & 15;  // A: M row / B,C,D: N col (batch)
  const int kblk = l >> 4;   // A,B: k-block of 8 / C,D: row-block of 4

  const int b0 = blockIdx.x * BB;

  // ---- per-group weight A-fragments (one layer only), pre-scaled ----
  f16x8 wIn[4][2], wRec[4][2];
  f32x4 bias[4];
#pragma unroll
  for (int gt = 0; gt < 4; ++gt) {
    const float sc = (gt == 2) ? (2.0f * LOG2E) : (-LOG2E);
    const int g = gt * 64 + wl * 16 + row16;
    if (grp == 0) {
      f16x8 v;
#pragma unroll
      for (int j = 0; j < 8; ++j) {
        const int k = kblk * 8 + j;
        v[j] = (k < II) ? (_Float16)(w_ih0[g * II + k] * sc) : (_Float16)0.0f;
      }
      wIn[gt][0] = v;
#pragma unroll
      for (int ks = 0; ks < 2; ++ks) {
        const int ko = ks * 32 + kblk * 8;
        f16x8 vr;
#pragma unroll
        for (int j = 0; j < 8; ++j) vr[j] = (_Float16)(w_hh0[g * 64 + ko + j] * sc);
        wRec[gt][ks] = vr;
      }
    } else {
#pragma unroll
      for (int ks = 0; ks < 2; ++ks) {
        const int ko = ks * 32 + kblk * 8;
        f16x8 vi, vr;
#pragma unroll
        for (int j = 0; j < 8; ++j) vi[j] = (_Float16)(w_ih1[g * 64 + ko + j] * sc);
#pragma unroll
        for (int j = 0; j < 8; ++j) vr[j] = (_Float16)(w_hh1[g * 64 + ko + j] * sc);
        wIn[gt][ks] = vi;
        wRec[gt][ks] = vr;
      }
    }
    const int gb = gt * 64 + wl * 16 + kblk * 4;  // C/D row base
#pragma unroll
    for (int r = 0; r < 4; ++r) {
      bias[gt][r] = (grp == 0) ? (b_ih0[gb + r] + b_hh0[gb + r]) * sc
                               : (b_ih1[gb + r] + b_hh1[gb + r]) * sc;
    }
  }

  for (int i = tid; i < 12544 / 4; i += NTHREADS) ((int*)smem)[i] = 0;

  // x staging: BB*II = 224 slots (all within grp0's waves, tid<224<256)
  const int n0 = tid / II, k0 = tid - n0 * II;
  const bool hasx = tid < BB * II;
  const float* xp0 = x + (size_t)(b0 + (hasx ? n0 : 0)) * (TT * II) + k0;

  __syncthreads();  // zeros done
  if (hasx) XS[n0 * XP + k0] = (_Float16)xp0[0];
  __syncthreads();  // x(0) staged

  f32x4 cs = {0.f, 0.f, 0.f, 0.f};

  const int boff = row16 * HP + kblk * 8;           // B-frag offset (halfs)
  const int woff = row16 * HP + wl * 16 + kblk * 4; // C/D publish offset

  // ============ prologue t=0: grp0 computes h0(0) ============
  if (grp == 0) {
    f32x4 acc[4];
    const f16x8 bx = *(const f16x8*)(XS + row16 * XP + kblk * 8);
    const f16x8 bhA = *(const f16x8*)(H0 + HSTR + boff);  // zeros
    const f16x8 bhB = *(const f16x8*)(H0 + HSTR + 32 + boff);
    __builtin_amdgcn_s_setprio(1);
#pragma unroll
    for (int gt = 0; gt < 4; ++gt) {
      acc[gt] = MFMA16(wIn[gt][0], bx, bias[gt]);
      acc[gt] = MFMA16(wRec[gt][0], bhA, acc[gt]);
      acc[gt] = MFMA16(wRec[gt][1], bhB, acc[gt]);
    }
    __builtin_amdgcn_s_setprio(0);
    const float xn = hasx ? (float)xp0[II] : 0.0f;  // x(1)
    const f16x4 hp = lstm_act(acc[0], acc[1], acc[2], acc[3], cs);
    *(f16x4*)(H0 + woff) = hp;  // H0[0]
    if (hasx) XS[XSTR + n0 * XP + k0] = (_Float16)xn;
  }
  __syncthreads();

  // ============ main loop t=1..TT-1: grp0 L0(t), grp1 L1(t-1) ============
#pragma unroll 2
  for (int t = 1; t < TT; ++t) {
    const int pc = t & 1, pp = pc ^ 1;
    if (grp == 0) {
      f32x4 acc[4];
      const f16x8 bx = *(const f16x8*)(XS + pc * XSTR + row16 * XP + kblk * 8);
      const f16x8 bhA = *(const f16x8*)(H0 + pp * HSTR + boff);
      const f16x8 bhB = *(const f16x8*)(H0 + pp * HSTR + 32 + boff);
      __builtin_amdgcn_s_setprio(1);
#pragma unroll
      for (int gt = 0; gt < 4; ++gt) {
        acc[gt] = MFMA16(wIn[gt][0], bx, bias[gt]);
        acc[gt] = MFMA16(wRec[gt][0], bhA, acc[gt]);
        acc[gt] = MFMA16(wRec[gt][1], bhB, acc[gt]);
      }
      __builtin_amdgcn_s_setprio(0);
      // branchless clamped prefetch of x(t+1)
      const int tn = (t + 1 < TT) ? (t + 1) : (TT - 1);
      const float xn = hasx ? xp0[(size_t)tn * II] : 0.0f;
      const f16x4 hp = lstm_act(acc[0], acc[1], acc[2], acc[3], cs);
      *(f16x4*)(H0 + pc * HSTR + woff) = hp;  // h0(t)
      if (hasx) XS[pp * XSTR + n0 * XP + k0] = (_Float16)xn;
    } else {
      f32x4 acc[4];
      const f16x8 bgA = *(const f16x8*)(H0 + pp * HSTR + boff);  // h0(t-1)
      const f16x8 bgB = *(const f16x8*)(H0 + pp * HSTR + 32 + boff);
      const f16x8 bhA = *(const f16x8*)(H1 + pc * HSTR + boff);  // h1(t-2)
      const f16x8 bhB = *(const f16x8*)(H1 + pc * HSTR + 32 + boff);
      __builtin_amdgcn_s_setprio(1);
#pragma unroll
      for (int gt = 0; gt < 4; ++gt) {
        acc[gt] = MFMA16(wIn[gt][0], bgA, bias[gt]);
        acc[gt] = MFMA16(wIn[gt][1], bgB, acc[gt]);
        acc[gt] = MFMA16(wRec[gt][0], bhA, acc[gt]);
        acc[gt] = MFMA16(wRec[gt][1], bhB, acc[gt]);
      }
      __builtin_amdgcn_s_setprio(0);
      const f16x4 hp = lstm_act(acc[0], acc[1], acc[2], acc[3], cs);
      *(f16x4*)(H1 + pp * HSTR + woff) = hp;  // h1(t-1)
    }
    __syncthreads();
  }

  // ============ epilogue: grp1 computes h1(TT-1) ============
  if (grp == 1) {  // pc=0, pp=1
    f32x4 acc[4];
    const f16x8 bgA = *(const f16x8*)(H0 + HSTR + boff);  // h0(TT-1)
    const f16x8 bgB = *(const f16x8*)(H0 + HSTR + 32 + boff);
    const f16x8 bhA = *(const f16x8*)(H1 + boff);          // h1(TT-2)
    const f16x8 bhB = *(const f16x8*)(H1 + 32 + boff);
    __builtin_amdgcn_s_setprio(1);
#pragma unroll
    for (int gt = 0; gt < 4; ++gt) {
      acc[gt] = MFMA16(wIn[gt][0], bgA, bias[gt]);
      acc[gt] = MFMA16(wIn[gt][1], bgB, acc[gt]);
      acc[gt] = MFMA16(wRec[gt][0], bhA, acc[gt]);
      acc[gt] = MFMA16(wRec[gt][1], bhB, acc[gt]);
    }
    __builtin_amdgcn_s_setprio(0);
    const f16x4 hp = lstm_act(acc[0], acc[1], acc[2], acc[3], cs);
    *(f16x4*)(H1 + HSTR + woff) = hp;  // h1(TT-1)
  }
  __syncthreads();

  // ============ FC head (512 threads) ============
  const _Float16* h1f = H1 + HSTR;       // h1(TT-1), parity 1
  float* zbuf = (float*)(smem + 4864);   // overlays H0 (dead), 16*64*4=4096B
  {
    float4 w1r[16];
#pragma unroll
    for (int k4 = 0; k4 < 16; ++k4)
      w1r[k4] = *(const float4*)(w_fc1 + l * 64 + k4 * 4);
    const float b1l = b_fc1[l];
#pragma unroll
    for (int bi = 0; bi < 2; ++bi) {
      const int n = wv * 2 + bi;
      float s = b1l;
#pragma unroll
      for (int k4 = 0; k4 < 16; ++k4) {
        const float4 wq = w1r[k4];
        s = fmaf((float)h1f[n * HP + k4 * 4 + 0], wq.x, s);
        s = fmaf((float)h1f[n * HP + k4 * 4 + 1], wq.y, s);
        s = fmaf((float)h1f[n * HP + k4 * 4 + 2], wq.z, s);
        s = fmaf((float)h1f[n * HP + k4 * 4 + 3], wq.w, s);
      }
      zbuf[n * 64 + l] = fmaxf(s, 0.0f);
    }
  }
  __syncthreads();
  if (tid < 2 * BB) {
    const int n = tid >> 1, cc = tid & 1;
    float s = b_fc2[cc];
    for (int j = 0; j < 64; ++j) s = fmaf(w_fc2[cc * 64 + j], zbuf[n * 64 + j], s);
    out[(size_t)(b0 + n) * 2 + cc] = s;
  }
}

extern "C" void kernel_launch(void* const* d_in, const int* in_sizes, int n_in,
                              void* d_out, int out_size, void* d_ws, size_t ws_size,
                              hipStream_t stream) {
  (void)in_sizes; (void)n_in; (void)d_ws; (void)ws_size; (void)out_size;
  const float* x = (const float*)d_in[0];
  const float* w_ih0 = (const float*)d_in[1];
  const float* w_hh0 = (const float*)d_in[2];
  const float* b_ih0 = (const float*)d_in[3];
  const float* b_hh0 = (const float*)d_in[4];
  const float* w_ih1 = (const float*)d_in[5];
  const float* w_hh1 = (const float*)d_in[6];
  const float* b_ih1 = (const float*)d_in[7];
  const float* b_hh1 = (const float*)d_in[8];
  const float* w_fc1 = (const float*)d_in[9];
  const float* b_fc1 = (const float*)d_in[10];
  const float* w_fc2 = (const float*)d_in[11];
  const float* b_fc2 = (const float*)d_in[12];

  fused_lstm<<<dim3(8192 / BB), dim3(NTHREADS), 0, stream>>>(
      x, w_ih0, w_hh0, b_ih0, b_hh0, w_ih1, w_hh1, b_ih1, b_hh1,
      w_fc1, b_fc1, w_fc2, b_fc2, (float*)d_out);
}

// Round 15
// 317.954 us; speedup vs baseline: 1.3906x; 1.3906x over previous
//
#include <hip/hip_runtime.h>

// R15 = R10 (best, 318us) with ONLY the safe piece of R14 kept: bias rides as
// the MFMA C operand (no per-step acc init v_movs; FP order identical).
// Pitches reverted to the 16B-aligned HP=72/XP=40 (R14's 76/44 broke b128
// alignment -> split LDS ops -> 40% regression despite killing conflicts).
// Structure: 8-wave layer-split block, BB=16, skewed layers, 1 barrier/step,
// weights in regs, rational 7-trans packed-f32 activations, setprio on MFMA.

#define TT 256
#define II 14
#define BB 16
#define NTHREADS 512
#define XP 40        // xs row pitch (halfs), 80B (16B-aligned)
#define HP 72        // h row pitch (halfs), 144B (16B-aligned)
#define HSTR 1152    // halfs per H buffer (16*72)
#define XSTR 640     // halfs per XS buffer (16*40)
#define LOG2E 1.44269504088896340736f

typedef _Float16 f16x8 __attribute__((ext_vector_type(8)));
typedef _Float16 f16x4 __attribute__((ext_vector_type(4)));
typedef _Float16 f16x2 __attribute__((ext_vector_type(2)));
typedef float f32x4 __attribute__((ext_vector_type(4)));
typedef float f32x2 __attribute__((ext_vector_type(2)));

__device__ __forceinline__ f32x4 MFMA16(f16x8 a, f16x8 b, f32x4 c) {
  return __builtin_amdgcn_mfma_f32_16x16x32_f16(a, b, c, 0, 0, 0);
}

__device__ __forceinline__ float ex2(float x) {
#if __has_builtin(__builtin_amdgcn_exp2f)
  return __builtin_amdgcn_exp2f(x);
#else
  float r; asm("v_exp_f32 %0, %1" : "=v"(r) : "v"(x)); return r;
#endif
}
__device__ __forceinline__ float rcp_(float x) {
#if __has_builtin(__builtin_amdgcn_rcpf)
  return __builtin_amdgcn_rcpf(x);
#else
  float r; asm("v_rcp_f32 %0, %1" : "=v"(r) : "v"(x)); return r;
#endif
}
__device__ __forceinline__ f16x2 cvt_pk(float a, float b) {
#if __has_builtin(__builtin_amdgcn_cvt_pkrtz)
  return __builtin_bit_cast(f16x2, __builtin_amdgcn_cvt_pkrtz(a, b));
#else
  f16x2 r; r[0] = (_Float16)a; r[1] = (_Float16)b; return r;
#endif
}

// Pre-scaled gates (i,f,o: *-log2e ; g: *2log2e), u = 2^s (R7 derivation).
__device__ __forceinline__ f16x4 lstm_act(f32x4 si, f32x4 sf, f32x4 sg, f32x4 so,
                                          f32x4& cs) {
  f16x4 hp;
#pragma unroll
  for (int p = 0; p < 2; ++p) {
    f32x2 ui, uf, ug, uo;
    ui.x = ex2(si[2 * p]); ui.y = ex2(si[2 * p + 1]);
    uf.x = ex2(sf[2 * p]); uf.y = ex2(sf[2 * p + 1]);
    ug.x = ex2(sg[2 * p]); ug.y = ex2(sg[2 * p + 1]);
    uo.x = ex2(so[2 * p]); uo.y = ex2(so[2 * p + 1]);
    const f32x2 one = {1.0f, 1.0f};
    const f32x2 fi = ui + one;
    const f32x2 ff = uf + one;
    const f32x2 fg = ug + one;
    const f32x2 pig = fi * fg;
    f32x2 cv; cv.x = cs[2 * p]; cv.y = cs[2 * p + 1];
    const f32x2 num = cv * pig + (ug - one) * ff;
    const f32x2 den = pig * ff;
    f32x2 rd; rd.x = rcp_(den.x); rd.y = rcp_(den.y);
    const f32x2 c = num * rd;
    cs[2 * p] = c.x; cs[2 * p + 1] = c.y;
    const f32x2 ctl = c * (f32x2){2.0f * LOG2E, 2.0f * LOG2E};
    f32x2 ut; ut.x = ex2(ctl.x); ut.y = ex2(ctl.y);
    const f32x2 dh = (uo + one) * (ut + one);
    f32x2 rh; rh.x = rcp_(dh.x); rh.y = rcp_(dh.y);
    const f32x2 h = (ut - one) * rh;
    const f16x2 h2 = cvt_pk(h.x, h.y);
    hp[2 * p] = h2[0];
    hp[2 * p + 1] = h2[1];
  }
  return hp;
}

__global__ void __launch_bounds__(NTHREADS, 4) fused_lstm(
    const float* __restrict__ x,
    const float* __restrict__ w_ih0, const float* __restrict__ w_hh0,
    const float* __restrict__ b_ih0, const float* __restrict__ b_hh0,
    const float* __restrict__ w_ih1, const float* __restrict__ w_hh1,
    const float* __restrict__ b_ih1, const float* __restrict__ b_hh1,
    const float* __restrict__ w_fc1, const float* __restrict__ b_fc1,
    const float* __restrict__ w_fc2, const float* __restrict__ b_fc2,
    float* __restrict__ out) {
  // LDS bytes: H1[2] @0 (2x2304) ; H0[2] @4608 (2x2304) ; XS[2] @9216 (2x1280)
  __shared__ char smem[11776];
  _Float16* H1 = (_Float16*)smem;
  _Float16* H0 = (_Float16*)(smem + 4608);
  _Float16* XS = (_Float16*)(smem + 9216);

  const int tid = threadIdx.x;
  const int wv = tid >> 6;
  const int grp = wv >> 2;   // 0: layer-0 waves, 1: layer-1 waves
  const int wl = wv & 3;     // hidden-tile index (16 units)
  const int l = tid & 63;
  const int row16 = l & 15;  // A: M row / B,C,D: N col (batch)
  const int kblk = l >> 4;   // A,B: k-block of 8 / C,D: row-block of 4

  const int b0 = blockIdx.x * BB;

  // ---- per-group weight A-fragments (one layer only), pre-scaled ----
  f16x8 wIn[4][2], wRec[4][2];
  f32x4 bias[4];
#pragma unroll
  for (int gt = 0; gt < 4; ++gt) {
    const float sc = (gt == 2) ? (2.0f * LOG2E) : (-LOG2E);
    const int g = gt * 64 + wl * 16 + row16;
    if (grp == 0) {
      f16x8 v;
#pragma unroll
      for (int j = 0; j < 8; ++j) {
        const int k = kblk * 8 + j;
        v[j] = (k < II) ? (_Float16)(w_ih0[g * II + k] * sc) : (_Float16)0.0f;
      }
      wIn[gt][0] = v;
#pragma unroll
      for (int ks = 0; ks < 2; ++ks) {
        const int ko = ks * 32 + kblk * 8;
        f16x8 vr;
#pragma unroll
        for (int j = 0; j < 8; ++j) vr[j] = (_Float16)(w_hh0[g * 64 + ko + j] * sc);
        wRec[gt][ks] = vr;
      }
    } else {
#pragma unroll
      for (int ks = 0; ks < 2; ++ks) {
        const int ko = ks * 32 + kblk * 8;
        f16x8 vi, vr;
#pragma unroll
        for (int j = 0; j < 8; ++j) vi[j] = (_Float16)(w_ih1[g * 64 + ko + j] * sc);
#pragma unroll
        for (int j = 0; j < 8; ++j) vr[j] = (_Float16)(w_hh1[g * 64 + ko + j] * sc);
        wIn[gt][ks] = vi;
        wRec[gt][ks] = vr;
      }
    }
    const int gb = gt * 64 + wl * 16 + kblk * 4;  // C/D row base
#pragma unroll
    for (int r = 0; r < 4; ++r) {
      bias[gt][r] = (grp == 0) ? (b_ih0[gb + r] + b_hh0[gb + r]) * sc
                               : (b_ih1[gb + r] + b_hh1[gb + r]) * sc;
    }
  }

  for (int i = tid; i < 11776 / 4; i += NTHREADS) ((int*)smem)[i] = 0;

  // x staging: BB*II = 224 slots (all within grp0's waves, tid<224<256)
  const int n0 = tid / II, k0 = tid - n0 * II;
  const bool hasx = tid < BB * II;
  const float* xp0 = x + (size_t)(b0 + (hasx ? n0 : 0)) * (TT * II) + k0;

  __syncthreads();  // zeros done
  if (hasx) XS[n0 * XP + k0] = (_Float16)xp0[0];
  __syncthreads();  // x(0) staged

  f32x4 cs = {0.f, 0.f, 0.f, 0.f};

  const int boff = row16 * HP + kblk * 8;           // B-frag offset (halfs)
  const int woff = row16 * HP + wl * 16 + kblk * 4; // C/D publish offset

  // ============ prologue t=0: grp0 computes h0(0) ============
  if (grp == 0) {
    f32x4 acc[4];
    const f16x8 bx = *(const f16x8*)(XS + row16 * XP + kblk * 8);
    const f16x8 bhA = *(const f16x8*)(H0 + HSTR + boff);  // zeros
    const f16x8 bhB = *(const f16x8*)(H0 + HSTR + 32 + boff);
    __builtin_amdgcn_s_setprio(1);
#pragma unroll
    for (int gt = 0; gt < 4; ++gt) {
      acc[gt] = MFMA16(wIn[gt][0], bx, bias[gt]);
      acc[gt] = MFMA16(wRec[gt][0], bhA, acc[gt]);
      acc[gt] = MFMA16(wRec[gt][1], bhB, acc[gt]);
    }
    __builtin_amdgcn_s_setprio(0);
    const float xn = hasx ? (float)xp0[II] : 0.0f;  // x(1)
    const f16x4 hp = lstm_act(acc[0], acc[1], acc[2], acc[3], cs);
    *(f16x4*)(H0 + woff) = hp;  // H0[0]
    if (hasx) XS[XSTR + n0 * XP + k0] = (_Float16)xn;
  }
  __syncthreads();

  // ============ main loop t=1..TT-1: grp0 L0(t), grp1 L1(t-1) ============
#pragma unroll 2
  for (int t = 1; t < TT; ++t) {
    const int pc = t & 1, pp = pc ^ 1;
    if (grp == 0) {
      f32x4 acc[4];
      const f16x8 bx = *(const f16x8*)(XS + pc * XSTR + row16 * XP + kblk * 8);
      const f16x8 bhA = *(const f16x8*)(H0 + pp * HSTR + boff);
      const f16x8 bhB = *(const f16x8*)(H0 + pp * HSTR + 32 + boff);
      __builtin_amdgcn_s_setprio(1);
#pragma unroll
      for (int gt = 0; gt < 4; ++gt) {
        acc[gt] = MFMA16(wIn[gt][0], bx, bias[gt]);
        acc[gt] = MFMA16(wRec[gt][0], bhA, acc[gt]);
        acc[gt] = MFMA16(wRec[gt][1], bhB, acc[gt]);
      }
      __builtin_amdgcn_s_setprio(0);
      // branchless clamped prefetch of x(t+1)
      const int tn = (t + 1 < TT) ? (t + 1) : (TT - 1);
      const float xn = hasx ? xp0[(size_t)tn * II] : 0.0f;
      const f16x4 hp = lstm_act(acc[0], acc[1], acc[2], acc[3], cs);
      *(f16x4*)(H0 + pc * HSTR + woff) = hp;  // h0(t)
      if (hasx) XS[pp * XSTR + n0 * XP + k0] = (_Float16)xn;
    } else {
      f32x4 acc[4];
      const f16x8 bgA = *(const f16x8*)(H0 + pp * HSTR + boff);  // h0(t-1)
      const f16x8 bgB = *(const f16x8*)(H0 + pp * HSTR + 32 + boff);
      const f16x8 bhA = *(const f16x8*)(H1 + pc * HSTR + boff);  // h1(t-2)
      const f16x8 bhB = *(const f16x8*)(H1 + pc * HSTR + 32 + boff);
      __builtin_amdgcn_s_setprio(1);
#pragma unroll
      for (int gt = 0; gt < 4; ++gt) {
        acc[gt] = MFMA16(wIn[gt][0], bgA, bias[gt]);
        acc[gt] = MFMA16(wIn[gt][1], bgB, acc[gt]);
        acc[gt] = MFMA16(wRec[gt][0], bhA, acc[gt]);
        acc[gt] = MFMA16(wRec[gt][1], bhB, acc[gt]);
      }
      __builtin_amdgcn_s_setprio(0);
      const f16x4 hp = lstm_act(acc[0], acc[1], acc[2], acc[3], cs);
      *(f16x4*)(H1 + pp * HSTR + woff) = hp;  // h1(t-1)
    }
    __syncthreads();
  }

  // ============ epilogue: grp1 computes h1(TT-1) ============
  if (grp == 1) {  // pc=0, pp=1
    f32x4 acc[4];
    const f16x8 bgA = *(const f16x8*)(H0 + HSTR + boff);  // h0(TT-1)
    const f16x8 bgB = *(const f16x8*)(H0 + HSTR + 32 + boff);
    const f16x8 bhA = *(const f16x8*)(H1 + boff);          // h1(TT-2)
    const f16x8 bhB = *(const f16x8*)(H1 + 32 + boff);
    __builtin_amdgcn_s_setprio(1);
#pragma unroll
    for (int gt = 0; gt < 4; ++gt) {
      acc[gt] = MFMA16(wIn[gt][0], bgA, bias[gt]);
      acc[gt] = MFMA16(wIn[gt][1], bgB, acc[gt]);
      acc[gt] = MFMA16(wRec[gt][0], bhA, acc[gt]);
      acc[gt] = MFMA16(wRec[gt][1], bhB, acc[gt]);
    }
    __builtin_amdgcn_s_setprio(0);
    const f16x4 hp = lstm_act(acc[0], acc[1], acc[2], acc[3], cs);
    *(f16x4*)(H1 + HSTR + woff) = hp;  // h1(TT-1)
  }
  __syncthreads();

  // ============ FC head (512 threads) ============
  const _Float16* h1f = H1 + HSTR;       // h1(TT-1), parity 1
  float* zbuf = (float*)(smem + 4608);   // overlays H0 (dead)
  {
    float4 w1r[16];
#pragma unroll
    for (int k4 = 0; k4 < 16; ++k4)
      w1r[k4] = *(const float4*)(w_fc1 + l * 64 + k4 * 4);
    const float b1l = b_fc1[l];
#pragma unroll
    for (int bi = 0; bi < 2; ++bi) {
      const int n = wv * 2 + bi;
      float s = b1l;
#pragma unroll
      for (int k4 = 0; k4 < 16; ++k4) {
        const float4 wq = w1r[k4];
        s = fmaf((float)h1f[n * HP + k4 * 4 + 0], wq.x, s);
        s = fmaf((float)h1f[n * HP + k4 * 4 + 1], wq.y, s);
        s = fmaf((float)h1f[n * HP + k4 * 4 + 2], wq.z, s);
        s = fmaf((float)h1f[n * HP + k4 * 4 + 3], wq.w, s);
      }
      zbuf[n * 64 + l] = fmaxf(s, 0.0f);
    }
  }
  __syncthreads();
  if (tid < 2 * BB) {
    const int n = tid >> 1, cc = tid & 1;
    float s = b_fc2[cc];
    for (int j = 0; j < 64; ++j) s = fmaf(w_fc2[cc * 64 + j], zbuf[n * 64 + j], s);
    out[(size_t)(b0 + n) * 2 + cc] = s;
  }
}

extern "C" void kernel_launch(void* const* d_in, const int* in_sizes, int n_in,
                              void* d_out, int out_size, void* d_ws, size_t ws_size,
                              hipStream_t stream) {
  (void)in_sizes; (void)n_in; (void)d_ws; (void)ws_size; (void)out_size;
  const float* x = (const float*)d_in[0];
  const float* w_ih0 = (const float*)d_in[1];
  const float* w_hh0 = (const float*)d_in[2];
  const float* b_ih0 = (const float*)d_in[3];
  const float* b_hh0 = (const float*)d_in[4];
  const float* w_ih1 = (const float*)d_in[5];
  const float* w_hh1 = (const float*)d_in[6];
  const float* b_ih1 = (const float*)d_in[7];
  const float* b_hh1 = (const float*)d_in[8];
  const float* w_fc1 = (const float*)d_in[9];
  const float* b_fc1 = (const float*)d_in[10];
  const float* w_fc2 = (const float*)d_in[11];
  const float* b_fc2 = (const float*)d_in[12];

  fused_lstm<<<dim3(8192 / BB), dim3(NTHREADS), 0, stream>>>(
      x, w_ih0, w_hh0, b_ih0, b_hh0, w_ih1, w_hh1, b_ih1, b_hh1,
      w_fc1, b_fc1, w_fc2, b_fc2, (float*)d_out);
}